// Round 5
// baseline (84.263 us; speedup 1.0000x reference)
//
#include <hip/hip_runtime.h>
#include <cstdint>
#include <cstddef>

// Problem constants
#define B_    32
#define N_    5023
#define F_    64
#define S_    9
#define OUT_  128
#define M_TOT (B_ * N_)        // 160736
#define K_    (S_ * F_)        // 576

// Workspace layout (bytes)
#define X_ELEMS   (B_ * N_ * F_)          // 10,287,104
#define WS_XB     0                        // bf16 x: 20,574,208 B
#define WS_WB     20574208                 // bf16 W: 147,456 B

typedef __attribute__((ext_vector_type(8))) short          bf16x8;
typedef __attribute__((ext_vector_type(4))) float          f32x4;
typedef __attribute__((ext_vector_type(8))) unsigned short u16x8;

// ---------------------------------------------------------------------------
// Fused fp32->bf16 (RNE) conversion for x and W in one grid.
// ---------------------------------------------------------------------------
__global__ void cvt_xw(const float* __restrict__ x, const float* __restrict__ W,
                       unsigned short* __restrict__ xb, unsigned short* __restrict__ Wb,
                       int nx8, int nw8) {
    const int i = blockIdx.x * blockDim.x + threadIdx.x;
    const float* src;
    unsigned short* dst;
    if (i < nx8) { src = x + (size_t)i * 8; dst = xb + (size_t)i * 8; }
    else {
        const int j = i - nx8;
        if (j >= nw8) return;
        src = W + (size_t)j * 8; dst = Wb + (size_t)j * 8;
    }
    const float4 v0 = ((const float4*)src)[0], v1 = ((const float4*)src)[1];
    const float vv[8] = {v0.x, v0.y, v0.z, v0.w, v1.x, v1.y, v1.z, v1.w};
    u16x8 r;
    #pragma unroll
    for (int k = 0; k < 8; ++k) {
        uint32_t u = __float_as_uint(vv[k]);
        u = u + 0x7fffu + ((u >> 16) & 1u);
        r[k] = (unsigned short)(u >> 16);
    }
    *(u16x8*)dst = r;
}

// ---------------------------------------------------------------------------
// Main MFMA kernel, barrier-free K-loop, idx fully preloaded, A ring-3.
// Block: 256 rows x 64 cols, 8 waves (one 32x64 tile each, 2x4 frags of
// mfma_f32_16x16x32_bf16). Grid: 628 row-tiles x 2 col-tiles = 1256.
//
// adj is read RAW (int64 or int32, uniform scalar probe per block; values
// fit in the low dword either way, so a dword load at j<<sh suffices).
// W: all 9 K-slabs staged once via global_load_lds, XOR-chunk-swizzled
//    (phys 16B chunk = logical ^ (o&7)) by pre-swizzling the global source.
//    Handoff: explicit s_waitcnt vmcnt(0) + ONE __syncthreads().
// A: gathered direct from bf16 xb; ring-3 register pipeline (A[s+3] issued
//    at step s after the MFMA cluster -> ~2 steps of latency slack), no idx
//    dependency in the loop.
// ---------------------------------------------------------------------------
__global__ __launch_bounds__(512, 4)
void spiral_mfma(const unsigned short* __restrict__ xb,
                 const void* __restrict__ adj,
                 const unsigned short* __restrict__ Wb,
                 const float* __restrict__ bias,
                 float* __restrict__ out) {
    __shared__ unsigned short Wlds[S_ * 64 * 64];   // 73,728 B

    const int tid = threadIdx.x;
    const int l   = tid & 63;
    const int w   = tid >> 6;                        // 0..7

    // Uniform dtype probe: odd 32-bit words of the first 8 int64 slots are
    // all zero iff adj is int64 (indices < 2^31). Scalar loads, broadcast.
    const int* aw = (const int*)adj;
    const int pv = aw[1] | aw[3] | aw[5] | aw[7] | aw[9] | aw[11] | aw[13] | aw[15];
    const int sh = (pv == 0) ? 3 : 2;               // byte shift per element
    const char* adjp = (const char*)adj;

    // XCD-chunked bijective swizzle (1256 = 8 * 157), col-tile fastest so
    // paired blocks (sharing A rows) land on the same XCD.
    const int bid  = blockIdx.x;
    const int nb   = (bid & 7) * 157 + (bid >> 3);
    const int rowT = nb >> 1, colT = nb & 1;
    const int m0   = rowT * 256;
    const int c0   = colT * 64;

    // A-gather bases: wave w owns rows [w*32, w*32+32)
    int    adjb[2];
    size_t xrb[2];
    #pragma unroll
    for (int mi = 0; mi < 2; ++mi) {
        int m = m0 + w * 32 + mi * 16 + (l & 15);
        if (m >= M_TOT) m = M_TOT - 1;
        adjb[mi] = m * S_;
        xrb[mi]  = (size_t)(m / N_) * (N_ * F_);
    }
    const int ko = (l >> 4) * 8;

    // Preload ALL spiral indices for this thread's rows (no idx dependency
    // remains in the K-loop). 18 dword loads, issued before W staging.
    int idxv[2][S_];
    #pragma unroll
    for (int mi = 0; mi < 2; ++mi)
        #pragma unroll
        for (int s = 0; s < S_; ++s)
            idxv[mi][s] = *(const int*)(adjp + ((size_t)(adjb[mi] + s) << sh));

    // bias (epilogue data, loaded early to overlap)
    float bs[4];
    #pragma unroll
    for (int ni = 0; ni < 4; ++ni) bs[ni] = bias[c0 + ni * 16 + (l & 15)];

    // Stage all 9 W slabs: wave w covers rows [w*8, w*8+8) of each slab,
    // lane l -> row +(l>>3), phys chunk (l&7); source pre-swizzled so
    // phys chunk p at row o holds logical chunk p^(o&7).
    #pragma unroll
    for (int s = 0; s < S_; ++s) {
        const int o = w * 8 + (l >> 3);
        const unsigned short* src =
            Wb + (size_t)(c0 + o) * K_ + s * F_ + ((l & 7) ^ ((l >> 3) & 7)) * 8;
        unsigned short* dst = &Wlds[(s * 64 + w * 8) * 64];
        __builtin_amdgcn_global_load_lds(
            (const __attribute__((address_space(1))) void*)src,
            (__attribute__((address_space(3))) void*)dst, 16, 0, 0);
    }

    f32x4 acc[2][4];
    #pragma unroll
    for (int mi = 0; mi < 2; ++mi)
        #pragma unroll
        for (int ni = 0; ni < 4; ++ni) {
            acc[mi][ni][0] = 0.f; acc[mi][ni][1] = 0.f;
            acc[mi][ni][2] = 0.f; acc[mi][ni][3] = 0.f;
        }

    // Handoff: explicit drain of this wave's LDS-DMA writes, then barrier.
    __builtin_amdgcn_sched_barrier(0);
    asm volatile("s_waitcnt vmcnt(0)" ::: "memory");
    __builtin_amdgcn_sched_barrier(0);
    __syncthreads();   // the ONLY barrier: all W slabs complete

    // A ring-3 prologue: A[0], A[1], A[2]
    bf16x8 a[3][2][2];
    #pragma unroll
    for (int s = 0; s < 3; ++s)
        #pragma unroll
        for (int mi = 0; mi < 2; ++mi) {
            const unsigned short* p =
                xb + xrb[mi] + (size_t)idxv[mi][s] * F_ + ko;
            a[s][mi][0] = *(const bf16x8*)p;
            a[s][mi][1] = *(const bf16x8*)(p + 32);
        }

    #pragma unroll
    for (int s = 0; s < S_; ++s) {
        const int cur = s % 3;

        __builtin_amdgcn_s_setprio(1);
        #pragma unroll
        for (int h = 0; h < 2; ++h) {
            bf16x8 bf[4];
            #pragma unroll
            for (int ni = 0; ni < 4; ++ni) {
                const int o = ni * 16 + (l & 15);          // o&7 == l&7
                const int c = h * 4 + (l >> 4);            // logical chunk
                const int p = c ^ (l & 7);                 // phys chunk
                bf[ni] = *(const bf16x8*)&Wlds[(s * 64 + o) * 64 + p * 8];
            }
            #pragma unroll
            for (int mi = 0; mi < 2; ++mi)
                #pragma unroll
                for (int ni = 0; ni < 4; ++ni)
                    acc[mi][ni] = __builtin_amdgcn_mfma_f32_16x16x32_bf16(
                        a[cur][mi][h], bf[ni], acc[mi][ni], 0, 0, 0);
        }
        __builtin_amdgcn_s_setprio(0);

        // Refill the slot just consumed with A[s+3] (WAR on the MFMA reads
        // keeps this after the cluster; ~2 full steps of slack before use).
        if (s + 3 < S_) {
            #pragma unroll
            for (int mi = 0; mi < 2; ++mi) {
                const unsigned short* p =
                    xb + xrb[mi] + (size_t)idxv[mi][s + 3] * F_ + ko;
                a[cur][mi][0] = *(const bf16x8*)p;
                a[cur][mi][1] = *(const bf16x8*)(p + 32);
            }
        }
    }

    // Epilogue: bias + ELU + row-mask + stores.
    // C/D: col = l&15, row = (l>>4)*4 + j per 16x16 frag.
    const int rb = m0 + w * 32 + (l >> 4) * 4;
    const int cb = c0 + (l & 15);
    #pragma unroll
    for (int mi = 0; mi < 2; ++mi) {
        #pragma unroll
        for (int j = 0; j < 4; ++j) {
            const int m = rb + mi * 16 + j;
            if (m < M_TOT) {
                const bool z = ((m % N_) == (N_ - 1));
                float* orow = out + (size_t)m * OUT_ + cb;
                #pragma unroll
                for (int ni = 0; ni < 4; ++ni) {
                    float v = acc[mi][ni][j] + bs[ni];
                    v = v > 0.f ? v : expm1f(v);
                    if (z) v = 0.f;
                    orow[ni * 16] = v;
                }
            }
        }
    }
}

extern "C" void kernel_launch(void* const* d_in, const int* in_sizes, int n_in,
                              void* d_out, int out_size, void* d_ws, size_t ws_size,
                              hipStream_t stream) {
    const float* x    = (const float*)d_in[0];
    const void*  adj  = d_in[1];
    const float* W    = (const float*)d_in[2];
    const float* bias = (const float*)d_in[3];
    float* out        = (float*)d_out;

    char* ws = (char*)d_ws;
    unsigned short* xb = (unsigned short*)(ws + WS_XB);
    unsigned short* Wb = (unsigned short*)(ws + WS_WB);

    const int nx8 = X_ELEMS / 8;          // 1,285,888
    const int nw8 = (OUT_ * K_) / 8;      // 9,216
    cvt_xw<<<(nx8 + nw8 + 255) / 256, 256, 0, stream>>>(x, W, xb, Wb, nx8, nw8);

    spiral_mfma<<<1256, 512, 0, stream>>>(xb, adj, Wb, bias, out);
}

// Round 6
// 74.308 us; speedup vs baseline: 1.1340x; 1.1340x over previous
//
#include <hip/hip_runtime.h>
#include <cstdint>
#include <cstddef>

// Problem constants
#define B_    32
#define N_    5023
#define F_    64
#define S_    9
#define OUT_  128
#define M_TOT (B_ * N_)        // 160736
#define K_    (S_ * F_)        // 576

// Workspace layout (bytes)
#define X_ELEMS   (B_ * N_ * F_)          // 10,287,104
#define WS_XB     0                        // bf16 x: 20,574,208 B
#define WS_WB     20574208                 // bf16 W: 147,456 B

typedef __attribute__((ext_vector_type(8))) short          bf16x8;
typedef __attribute__((ext_vector_type(4))) float          f32x4;
typedef __attribute__((ext_vector_type(8))) unsigned short u16x8;

// ---------------------------------------------------------------------------
// Fused fp32->bf16 (RNE) conversion for x and W in one grid.
// ---------------------------------------------------------------------------
__global__ void cvt_xw(const float* __restrict__ x, const float* __restrict__ W,
                       unsigned short* __restrict__ xb, unsigned short* __restrict__ Wb,
                       int nx8, int nw8) {
    const int i = blockIdx.x * blockDim.x + threadIdx.x;
    const float* src;
    unsigned short* dst;
    if (i < nx8) { src = x + (size_t)i * 8; dst = xb + (size_t)i * 8; }
    else {
        const int j = i - nx8;
        if (j >= nw8) return;
        src = W + (size_t)j * 8; dst = Wb + (size_t)j * 8;
    }
    const float4 v0 = ((const float4*)src)[0], v1 = ((const float4*)src)[1];
    const float vv[8] = {v0.x, v0.y, v0.z, v0.w, v1.x, v1.y, v1.z, v1.w};
    u16x8 r;
    #pragma unroll
    for (int k = 0; k < 8; ++k) {
        uint32_t u = __float_as_uint(vv[k]);
        u = u + 0x7fffu + ((u >> 16) & 1u);
        r[k] = (unsigned short)(u >> 16);
    }
    *(u16x8*)dst = r;
}

// ---------------------------------------------------------------------------
// Main MFMA kernel. Block: 256 rows x 64 cols, 8 waves (32x64 each, 2x4
// frags of mfma_f32_16x16x32_bf16). Grid: 628 row-tiles x 2 col-tiles.
//
// Spill-proof ring-3 A pipeline: named buffers aA/aB/aC, 9 steps fully
// macro-unrolled (every index a compile-time literal). idx fully preloaded
// from RAW adj (uniform dtype probe). W: all 9 K-slabs staged once via
// global_load_lds, XOR-chunk-swizzled by pre-swizzled global source;
// explicit s_waitcnt vmcnt(0) + ONE __syncthreads(); zero loop barriers.
// launch_bounds(512,3): VGPR cap 170 so the ring fits without scratch.
// ---------------------------------------------------------------------------
__global__ __launch_bounds__(512, 3)
void spiral_mfma(const unsigned short* __restrict__ xb,
                 const void* __restrict__ adj,
                 const unsigned short* __restrict__ Wb,
                 const float* __restrict__ bias,
                 float* __restrict__ out) {
    __shared__ unsigned short Wlds[S_ * 64 * 64];   // 73,728 B

    const int tid = threadIdx.x;
    const int l   = tid & 63;
    const int w   = tid >> 6;                        // 0..7

    // Uniform dtype probe: odd 32-bit words of the first 8 int64 slots are
    // all zero iff adj is int64 (indices < 2^31). Scalar loads, broadcast.
    const int* aw = (const int*)adj;
    const int pv = aw[1] | aw[3] | aw[5] | aw[7] | aw[9] | aw[11] | aw[13] | aw[15];
    const int sh = (pv == 0) ? 3 : 2;               // byte shift per element
    const char* adjp = (const char*)adj;

    // XCD-chunked bijective swizzle (1256 = 8 * 157), col-tile fastest so
    // paired blocks (sharing A rows) land on the same XCD.
    const int bid  = blockIdx.x;
    const int nb   = (bid & 7) * 157 + (bid >> 3);
    const int rowT = nb >> 1, colT = nb & 1;
    const int m0   = rowT * 256;
    const int c0   = colT * 64;

    // A-gather bases: wave w owns rows [w*32, w*32+32)
    uint32_t xrb[2];
    int      idxv[2][S_];
    #pragma unroll
    for (int mi = 0; mi < 2; ++mi) {
        int m = m0 + w * 32 + mi * 16 + (l & 15);
        if (m >= M_TOT) m = M_TOT - 1;
        const int adjb = m * S_;
        xrb[mi] = (uint32_t)(m / N_) * (N_ * F_);
        #pragma unroll
        for (int s = 0; s < S_; ++s)
            idxv[mi][s] = *(const int*)(adjp + ((size_t)(adjb + s) << sh));
    }
    const int ko = (l >> 4) * 8;

    // Stage all 9 W slabs: wave w covers rows [w*8, w*8+8) of each slab,
    // lane l -> row +(l>>3), phys chunk (l&7); source pre-swizzled so
    // phys chunk p at row o holds logical chunk p^(o&7).
    #pragma unroll
    for (int s = 0; s < S_; ++s) {
        const int o = w * 8 + (l >> 3);
        const unsigned short* src =
            Wb + (size_t)(c0 + o) * K_ + s * F_ + ((l & 7) ^ ((l >> 3) & 7)) * 8;
        unsigned short* dst = &Wlds[(s * 64 + w * 8) * 64];
        __builtin_amdgcn_global_load_lds(
            (const __attribute__((address_space(1))) void*)src,
            (__attribute__((address_space(3))) void*)dst, 16, 0, 0);
    }

    f32x4 acc[2][4];
    #pragma unroll
    for (int mi = 0; mi < 2; ++mi)
        #pragma unroll
        for (int ni = 0; ni < 4; ++ni) {
            acc[mi][ni][0] = 0.f; acc[mi][ni][1] = 0.f;
            acc[mi][ni][2] = 0.f; acc[mi][ni][3] = 0.f;
        }

    // Handoff: explicit drain of this wave's LDS-DMA writes, then barrier.
    __builtin_amdgcn_sched_barrier(0);
    asm volatile("s_waitcnt vmcnt(0)" ::: "memory");
    __builtin_amdgcn_sched_barrier(0);
    __syncthreads();   // the ONLY barrier: all W slabs complete

    // Ring-3 A pipeline, named buffers, literal indices everywhere.
    bf16x8 aA[2][2], aB[2][2], aC[2][2];

    #define LOAD_A(BUF, sidx)                                                   \
        do {                                                                    \
            _Pragma("unroll")                                                   \
            for (int mi = 0; mi < 2; ++mi) {                                    \
                const unsigned short* p =                                       \
                    xb + xrb[mi] + (uint32_t)idxv[mi][(sidx)] * F_ + ko;        \
                BUF[mi][0] = *(const bf16x8*)p;                                 \
                BUF[mi][1] = *(const bf16x8*)(p + 32);                          \
            }                                                                   \
        } while (0)

    #define COMPUTE(s_, BUF)                                                    \
        do {                                                                    \
            __builtin_amdgcn_s_setprio(1);                                      \
            _Pragma("unroll")                                                   \
            for (int h = 0; h < 2; ++h) {                                       \
                bf16x8 bf[4];                                                   \
                _Pragma("unroll")                                               \
                for (int ni = 0; ni < 4; ++ni) {                                \
                    const int o  = ni * 16 + (l & 15);     /* o&7 == l&7 */     \
                    const int c  = h * 4 + (l >> 4);       /* logical chunk */  \
                    const int p_ = c ^ (l & 7);            /* phys chunk   */   \
                    bf[ni] = *(const bf16x8*)&Wlds[((s_) * 64 + o) * 64 + p_ * 8]; \
                }                                                               \
                _Pragma("unroll")                                               \
                for (int mi = 0; mi < 2; ++mi)                                  \
                    _Pragma("unroll")                                           \
                    for (int ni = 0; ni < 4; ++ni)                              \
                        acc[mi][ni] = __builtin_amdgcn_mfma_f32_16x16x32_bf16(  \
                            BUF[mi][h], bf[ni], acc[mi][ni], 0, 0, 0);          \
            }                                                                   \
            __builtin_amdgcn_s_setprio(0);                                      \
        } while (0)

    LOAD_A(aA, 0);
    LOAD_A(aB, 1);
    LOAD_A(aC, 2);

    COMPUTE(0, aA); LOAD_A(aA, 3);
    COMPUTE(1, aB); LOAD_A(aB, 4);
    COMPUTE(2, aC); LOAD_A(aC, 5);
    COMPUTE(3, aA); LOAD_A(aA, 6);
    COMPUTE(4, aB); LOAD_A(aB, 7);
    COMPUTE(5, aC); LOAD_A(aC, 8);
    COMPUTE(6, aA);
    COMPUTE(7, aB);
    COMPUTE(8, aC);

    #undef LOAD_A
    #undef COMPUTE

    // Epilogue: bias + ELU + row-mask + stores.
    // C/D: col = l&15, row = (l>>4)*4 + j per 16x16 frag.
    float bs[4];
    #pragma unroll
    for (int ni = 0; ni < 4; ++ni) bs[ni] = bias[c0 + ni * 16 + (l & 15)];

    const int rb = m0 + w * 32 + (l >> 4) * 4;
    const int cb = c0 + (l & 15);
    #pragma unroll
    for (int mi = 0; mi < 2; ++mi) {
        #pragma unroll
        for (int j = 0; j < 4; ++j) {
            const int m = rb + mi * 16 + j;
            if (m < M_TOT) {
                const bool z = ((m % N_) == (N_ - 1));
                float* orow = out + (size_t)m * OUT_ + cb;
                #pragma unroll
                for (int ni = 0; ni < 4; ++ni) {
                    float v = acc[mi][ni][j] + bs[ni];
                    v = v > 0.f ? v : expm1f(v);
                    if (z) v = 0.f;
                    orow[ni * 16] = v;
                }
            }
        }
    }
}

extern "C" void kernel_launch(void* const* d_in, const int* in_sizes, int n_in,
                              void* d_out, int out_size, void* d_ws, size_t ws_size,
                              hipStream_t stream) {
    const float* x    = (const float*)d_in[0];
    const void*  adj  = d_in[1];
    const float* W    = (const float*)d_in[2];
    const float* bias = (const float*)d_in[3];
    float* out        = (float*)d_out;

    char* ws = (char*)d_ws;
    unsigned short* xb = (unsigned short*)(ws + WS_XB);
    unsigned short* Wb = (unsigned short*)(ws + WS_WB);

    const int nx8 = X_ELEMS / 8;          // 1,285,888
    const int nw8 = (OUT_ * K_) / 8;      // 9,216
    cvt_xw<<<(nx8 + nw8 + 255) / 256, 256, 0, stream>>>(x, W, xb, Wb, nx8, nw8);

    spiral_mfma<<<1256, 512, 0, stream>>>(xb, adj, Wb, bias, out);
}

// Round 7
// 73.383 us; speedup vs baseline: 1.1483x; 1.0126x over previous
//
#include <hip/hip_runtime.h>
#include <cstdint>
#include <cstddef>

// Problem constants
#define B_    32
#define N_    5023
#define F_    64
#define S_    9
#define OUT_  128
#define M_TOT (B_ * N_)        // 160736
#define K_    (S_ * F_)        // 576

// Workspace layout (bytes)
#define X_ELEMS   (B_ * N_ * F_)          // 10,287,104
#define WS_XB     0                        // bf16 x: 20,574,208 B
#define WS_WB     20574208                 // bf16 W: 147,456 B

typedef __attribute__((ext_vector_type(8))) short          bf16x8;
typedef __attribute__((ext_vector_type(4))) float          f32x4;
typedef __attribute__((ext_vector_type(8))) unsigned short u16x8;

// ---------------------------------------------------------------------------
// Fused fp32->bf16 (RNE) conversion for x and W in one grid.
// ---------------------------------------------------------------------------
__global__ void cvt_xw(const float* __restrict__ x, const float* __restrict__ W,
                       unsigned short* __restrict__ xb, unsigned short* __restrict__ Wb,
                       int nx8, int nw8) {
    const int i = blockIdx.x * blockDim.x + threadIdx.x;
    const float* src;
    unsigned short* dst;
    if (i < nx8) { src = x + (size_t)i * 8; dst = xb + (size_t)i * 8; }
    else {
        const int j = i - nx8;
        if (j >= nw8) return;
        src = W + (size_t)j * 8; dst = Wb + (size_t)j * 8;
    }
    const float4 v0 = ((const float4*)src)[0], v1 = ((const float4*)src)[1];
    const float vv[8] = {v0.x, v0.y, v0.z, v0.w, v1.x, v1.y, v1.z, v1.w};
    u16x8 r;
    #pragma unroll
    for (int k = 0; k < 8; ++k) {
        uint32_t u = __float_as_uint(vv[k]);
        u = u + 0x7fffu + ((u >> 16) & 1u);
        r[k] = (unsigned short)(u >> 16);
    }
    *(u16x8*)dst = r;
}

// ---------------------------------------------------------------------------
// Main MFMA kernel. Block: 256 rows x 64 cols, 8 waves (32x64 each, 2x4
// frags of mfma_f32_16x16x32_bf16). Grid: 628 row-tiles x 2 col-tiles.
//
// Ring-3 A pipeline PINNED with sched_barrier(0) fences: loads for step
// s+3 are issued in region s and cannot sink below region s. Named ring
// buffers, fully macro-unrolled (literal indices). idx preloaded from RAW
// adj (uniform dtype probe). W: all 9 K-slabs staged once via
// global_load_lds, XOR-chunk-swizzled by pre-swizzled global source;
// explicit s_waitcnt vmcnt(0) + ONE __syncthreads(); zero loop barriers.
// ---------------------------------------------------------------------------
__global__ __launch_bounds__(512, 4)
void spiral_mfma(const unsigned short* __restrict__ xb,
                 const void* __restrict__ adj,
                 const unsigned short* __restrict__ Wb,
                 const float* __restrict__ bias,
                 float* __restrict__ out) {
    __shared__ unsigned short Wlds[S_ * 64 * 64];   // 73,728 B

    const int tid = threadIdx.x;
    const int l   = tid & 63;
    const int w   = tid >> 6;                        // 0..7

    // Uniform dtype probe: odd 32-bit words of the first 8 int64 slots are
    // all zero iff adj is int64 (indices < 2^31). Scalar loads, broadcast.
    const int* aw = (const int*)adj;
    const int pv = aw[1] | aw[3] | aw[5] | aw[7] | aw[9] | aw[11] | aw[13] | aw[15];
    const int sh = (pv == 0) ? 3 : 2;               // byte shift per element
    const char* adjp = (const char*)adj;

    // XCD-chunked bijective swizzle (1256 = 8 * 157), col-tile fastest so
    // paired blocks (sharing A rows) land on the same XCD.
    const int bid  = blockIdx.x;
    const int nb   = (bid & 7) * 157 + (bid >> 3);
    const int rowT = nb >> 1, colT = nb & 1;
    const int m0   = rowT * 256;
    const int c0   = colT * 64;

    // A-gather bases: wave w owns rows [w*32, w*32+32)
    uint32_t xrb[2];
    int      idxv[2][S_];
    #pragma unroll
    for (int mi = 0; mi < 2; ++mi) {
        int m = m0 + w * 32 + mi * 16 + (l & 15);
        if (m >= M_TOT) m = M_TOT - 1;
        const int adjb = m * S_;
        xrb[mi] = (uint32_t)(m / N_) * (N_ * F_);
        #pragma unroll
        for (int s = 0; s < S_; ++s)
            idxv[mi][s] = *(const int*)(adjp + ((size_t)(adjb + s) << sh));
    }
    const int ko = (l >> 4) * 8;

    // Stage all 9 W slabs: wave w covers rows [w*8, w*8+8) of each slab,
    // lane l -> row +(l>>3), phys chunk (l&7); source pre-swizzled so
    // phys chunk p at row o holds logical chunk p^(o&7).
    #pragma unroll
    for (int s = 0; s < S_; ++s) {
        const int o = w * 8 + (l >> 3);
        const unsigned short* src =
            Wb + (size_t)(c0 + o) * K_ + s * F_ + ((l & 7) ^ ((l >> 3) & 7)) * 8;
        unsigned short* dst = &Wlds[(s * 64 + w * 8) * 64];
        __builtin_amdgcn_global_load_lds(
            (const __attribute__((address_space(1))) void*)src,
            (__attribute__((address_space(3))) void*)dst, 16, 0, 0);
    }

    // Ring-3 A pipeline, named buffers, literal indices everywhere.
    bf16x8 aA[2][2], aB[2][2], aC[2][2];

    #define LOAD_A(BUF, sidx)                                                   \
        do {                                                                    \
            _Pragma("unroll")                                                   \
            for (int mi = 0; mi < 2; ++mi) {                                    \
                const unsigned short* p =                                       \
                    xb + xrb[mi] + (uint32_t)idxv[mi][(sidx)] * F_ + ko;        \
                BUF[mi][0] = *(const bf16x8*)p;                                 \
                BUF[mi][1] = *(const bf16x8*)(p + 32);                          \
            }                                                                   \
        } while (0)

    #define COMPUTE(s_, BUF)                                                    \
        do {                                                                    \
            __builtin_amdgcn_s_setprio(1);                                      \
            _Pragma("unroll")                                                   \
            for (int h = 0; h < 2; ++h) {                                       \
                bf16x8 bf[4];                                                   \
                _Pragma("unroll")                                               \
                for (int ni = 0; ni < 4; ++ni) {                                \
                    const int o  = ni * 16 + (l & 15);     /* o&7 == l&7 */     \
                    const int c  = h * 4 + (l >> 4);       /* logical chunk */  \
                    const int p_ = c ^ (l & 7);            /* phys chunk   */   \
                    bf[ni] = *(const bf16x8*)&Wlds[((s_) * 64 + o) * 64 + p_ * 8]; \
                }                                                               \
                _Pragma("unroll")                                               \
                for (int mi = 0; mi < 2; ++mi)                                  \
                    _Pragma("unroll")                                           \
                    for (int ni = 0; ni < 4; ++ni)                              \
                        acc[mi][ni] = __builtin_amdgcn_mfma_f32_16x16x32_bf16(  \
                            BUF[mi][h], bf[ni], acc[mi][ni], 0, 0, 0);          \
            }                                                                   \
            __builtin_amdgcn_s_setprio(0);                                      \
        } while (0)

    #define FENCE __builtin_amdgcn_sched_barrier(0)

    // Prologue ring fill issued BEFORE the drain: A[0..2] latency hides
    // under the W-DMA drain + barrier.
    LOAD_A(aA, 0);
    LOAD_A(aB, 1);
    LOAD_A(aC, 2);

    f32x4 acc[2][4];
    #pragma unroll
    for (int mi = 0; mi < 2; ++mi)
        #pragma unroll
        for (int ni = 0; ni < 4; ++ni) {
            acc[mi][ni][0] = 0.f; acc[mi][ni][1] = 0.f;
            acc[mi][ni][2] = 0.f; acc[mi][ni][3] = 0.f;
        }

    // Handoff: explicit drain of this wave's LDS-DMA writes, then barrier.
    FENCE;
    asm volatile("s_waitcnt vmcnt(0)" ::: "memory");
    FENCE;
    __syncthreads();   // the ONLY barrier: all W slabs complete

    // Pinned schedule: each region = {COMPUTE(s), LOAD_A(s+3)}; fences stop
    // the scheduler from sinking loads into later regions (the round-6
    // failure mode: VGPR=64 proved the ring had been collapsed).
    COMPUTE(0, aA); LOAD_A(aA, 3); FENCE;
    COMPUTE(1, aB); LOAD_A(aB, 4); FENCE;
    COMPUTE(2, aC); LOAD_A(aC, 5); FENCE;
    COMPUTE(3, aA); LOAD_A(aA, 6); FENCE;
    COMPUTE(4, aB); LOAD_A(aB, 7); FENCE;
    COMPUTE(5, aC); LOAD_A(aC, 8); FENCE;
    COMPUTE(6, aA);
    COMPUTE(7, aB);
    COMPUTE(8, aC);

    #undef LOAD_A
    #undef COMPUTE
    #undef FENCE

    // Epilogue: bias + fast ELU + row-mask + stores.
    // C/D: col = l&15, row = (l>>4)*4 + j per 16x16 frag.
    float bs[4];
    #pragma unroll
    for (int ni = 0; ni < 4; ++ni) bs[ni] = bias[c0 + ni * 16 + (l & 15)];

    const int rb = m0 + w * 32 + (l >> 4) * 4;
    const int cb = c0 + (l & 15);
    #pragma unroll
    for (int mi = 0; mi < 2; ++mi) {
        #pragma unroll
        for (int j = 0; j < 4; ++j) {
            const int m = rb + mi * 16 + j;
            if (m < M_TOT) {
                const bool z = ((m % N_) == (N_ - 1));
                float* orow = out + (size_t)m * OUT_ + cb;
                #pragma unroll
                for (int ni = 0; ni < 4; ++ni) {
                    float v = acc[mi][ni][j] + bs[ni];
                    // fast ELU: v_exp-based, ~1 ulp, fine vs 6.3e-2 threshold
                    const float e = __expf(v) - 1.0f;
                    v = v > 0.f ? v : e;
                    if (z) v = 0.f;
                    orow[ni * 16] = v;
                }
            }
        }
    }
}

extern "C" void kernel_launch(void* const* d_in, const int* in_sizes, int n_in,
                              void* d_out, int out_size, void* d_ws, size_t ws_size,
                              hipStream_t stream) {
    const float* x    = (const float*)d_in[0];
    const void*  adj  = d_in[1];
    const float* W    = (const float*)d_in[2];
    const float* bias = (const float*)d_in[3];
    float* out        = (float*)d_out;

    char* ws = (char*)d_ws;
    unsigned short* xb = (unsigned short*)(ws + WS_XB);
    unsigned short* Wb = (unsigned short*)(ws + WS_WB);

    const int nx8 = X_ELEMS / 8;          // 1,285,888
    const int nw8 = (OUT_ * K_) / 8;      // 9,216
    cvt_xw<<<(nx8 + nw8 + 255) / 256, 256, 0, stream>>>(x, W, xb, Wb, nx8, nw8);

    spiral_mfma<<<1256, 512, 0, stream>>>(xb, adj, Wb, bias, out);
}

// Round 8
// 72.392 us; speedup vs baseline: 1.1640x; 1.0137x over previous
//
#include <hip/hip_runtime.h>
#include <cstdint>
#include <cstddef>

// Problem constants
#define B_    32
#define N_    5023
#define F_    64
#define S_    9
#define OUT_  128
#define M_TOT (B_ * N_)        // 160736
#define K_    (S_ * F_)        // 576

// Workspace layout (bytes)
#define X_ELEMS   (B_ * N_ * F_)          // 10,287,104
#define WS_XB     0                        // bf16 x: 20,574,208 B
#define WS_WB     20574208                 // bf16 W: 147,456 B

typedef __attribute__((ext_vector_type(8))) short          bf16x8;
typedef __attribute__((ext_vector_type(4))) float          f32x4;
typedef __attribute__((ext_vector_type(8))) unsigned short u16x8;

// ---------------------------------------------------------------------------
// Fused fp32->bf16 (RNE) conversion for x and W in one grid.
// ---------------------------------------------------------------------------
__global__ void cvt_xw(const float* __restrict__ x, const float* __restrict__ W,
                       unsigned short* __restrict__ xb, unsigned short* __restrict__ Wb,
                       int nx8, int nw8) {
    const int i = blockIdx.x * blockDim.x + threadIdx.x;
    const float* src;
    unsigned short* dst;
    if (i < nx8) { src = x + (size_t)i * 8; dst = xb + (size_t)i * 8; }
    else {
        const int j = i - nx8;
        if (j >= nw8) return;
        src = W + (size_t)j * 8; dst = Wb + (size_t)j * 8;
    }
    const float4 v0 = ((const float4*)src)[0], v1 = ((const float4*)src)[1];
    const float vv[8] = {v0.x, v0.y, v0.z, v0.w, v1.x, v1.y, v1.z, v1.w};
    u16x8 r;
    #pragma unroll
    for (int k = 0; k < 8; ++k) {
        uint32_t u = __float_as_uint(vv[k]);
        u = u + 0x7fffu + ((u >> 16) & 1u);
        r[k] = (unsigned short)(u >> 16);
    }
    *(u16x8*)dst = r;
}

// ---------------------------------------------------------------------------
// Main MFMA kernel. Block: 256 rows x 64 cols, 8 waves (32x64 each, 2x4
// frags of mfma_f32_16x16x32_bf16). Grid: 628 row-tiles x 2 col-tiles.
//
// A-gather pipeline pinned with INLINE-ASM global_load_dwordx4 (volatile =>
// issue order fixed; r6/r7 showed C-level loads get sunk to their consumers
// regardless of sched_barrier). Counted s_waitcnt vmcnt(N) before each
// consuming MFMA cluster (m201/T3+T4 pattern), sched_barrier(0) after each
// wait (rule #18). All compiler-visible VMEM (idx, bias) is forced complete
// before the drain so the vmcnt counts stay exact in the loop.
// W: all 9 K-slabs staged once via global_load_lds, XOR-chunk-swizzled by
// pre-swizzled global source; explicit vmcnt(0) + ONE __syncthreads().
// ---------------------------------------------------------------------------
__global__ __launch_bounds__(512, 4)
void spiral_mfma(const unsigned short* __restrict__ xb,
                 const void* __restrict__ adj,
                 const unsigned short* __restrict__ Wb,
                 const float* __restrict__ bias,
                 float* __restrict__ out) {
    __shared__ unsigned short Wlds[S_ * 64 * 64];   // 73,728 B

    const int tid = threadIdx.x;
    const int l   = tid & 63;
    const int w   = tid >> 6;                        // 0..7

    // Uniform dtype probe: odd 32-bit words of the first 8 int64 slots are
    // all zero iff adj is int64 (indices < 2^31). Scalar loads, broadcast.
    const int* aw = (const int*)adj;
    const int pv = aw[1] | aw[3] | aw[5] | aw[7] | aw[9] | aw[11] | aw[13] | aw[15];
    const int sh = (pv == 0) ? 3 : 2;               // byte shift per element
    const char* adjp = (const char*)adj;

    // XCD-chunked bijective swizzle (1256 = 8 * 157), col-tile fastest so
    // paired blocks (sharing A rows) land on the same XCD.
    const int bid  = blockIdx.x;
    const int nb   = (bid & 7) * 157 + (bid >> 3);
    const int rowT = nb >> 1, colT = nb & 1;
    const int m0   = rowT * 256;
    const int c0   = colT * 64;

    // A-gather bases: wave w owns rows [w*32, w*32+32)
    uint32_t xrb[2];
    int      idxv[2][S_];
    #pragma unroll
    for (int mi = 0; mi < 2; ++mi) {
        int m = m0 + w * 32 + mi * 16 + (l & 15);
        if (m >= M_TOT) m = M_TOT - 1;
        const int adjb = m * S_;
        xrb[mi] = (uint32_t)(m / N_) * (N_ * F_);
        #pragma unroll
        for (int s = 0; s < S_; ++s)
            idxv[mi][s] = *(const int*)(adjp + ((size_t)(adjb + s) << sh));
    }
    const int ko = (l >> 4) * 8;

    // Stage all 9 W slabs: wave w covers rows [w*8, w*8+8) of each slab,
    // lane l -> row +(l>>3), phys chunk (l&7); source pre-swizzled so
    // phys chunk p at row o holds logical chunk p^(o&7).
    #pragma unroll
    for (int s = 0; s < S_; ++s) {
        const int o = w * 8 + (l >> 3);
        const unsigned short* src =
            Wb + (size_t)(c0 + o) * K_ + s * F_ + ((l & 7) ^ ((l >> 3) & 7)) * 8;
        unsigned short* dst = &Wlds[(s * 64 + w * 8) * 64];
        __builtin_amdgcn_global_load_lds(
            (const __attribute__((address_space(1))) void*)src,
            (__attribute__((address_space(3))) void*)dst, 16, 0, 0);
    }

    // bias: packed f32x4 + keep-alive so the loads complete BEFORE the drain
    // (no compiler VMEM may appear between counted asm loads in the loop).
    f32x4 bsv;
    bsv[0] = bias[c0 +  0 + (l & 15)];
    bsv[1] = bias[c0 + 16 + (l & 15)];
    bsv[2] = bias[c0 + 32 + (l & 15)];
    bsv[3] = bias[c0 + 48 + (l & 15)];
    asm volatile("" : "+v"(bsv));   // force materialization here

    // Ring-3 A buffers, loaded by PINNED inline-asm global loads.
    bf16x8 aA[2][2], aB[2][2], aC[2][2];

    #define LOAD_A(BUF, sidx)                                                   \
        do {                                                                    \
            _Pragma("unroll")                                                   \
            for (int mi = 0; mi < 2; ++mi) {                                    \
                const unsigned short* p_ =                                      \
                    xb + xrb[mi] + (uint32_t)idxv[mi][(sidx)] * F_ + ko;        \
                asm volatile("global_load_dwordx4 %0, %2, off\n\t"              \
                             "global_load_dwordx4 %1, %2, off offset:64"        \
                             : "=&v"(BUF[mi][0]), "=&v"(BUF[mi][1])             \
                             : "v"(p_)                                          \
                             : "memory");                                       \
            }                                                                   \
        } while (0)

    #define WAITA(N_)                                                           \
        do {                                                                    \
            asm volatile("s_waitcnt vmcnt(" #N_ ")" ::: "memory");              \
            __builtin_amdgcn_sched_barrier(0);                                  \
        } while (0)

    #define COMPUTE(s_, BUF)                                                    \
        do {                                                                    \
            __builtin_amdgcn_s_setprio(1);                                      \
            _Pragma("unroll")                                                   \
            for (int h = 0; h < 2; ++h) {                                       \
                bf16x8 bf[4];                                                   \
                _Pragma("unroll")                                               \
                for (int ni = 0; ni < 4; ++ni) {                                \
                    const int o  = ni * 16 + (l & 15);     /* o&7 == l&7 */     \
                    const int c  = h * 4 + (l >> 4);       /* logical chunk */  \
                    const int p_ = c ^ (l & 7);            /* phys chunk   */   \
                    bf[ni] = *(const bf16x8*)&Wlds[((s_) * 64 + o) * 64 + p_ * 8]; \
                }                                                               \
                _Pragma("unroll")                                               \
                for (int mi = 0; mi < 2; ++mi)                                  \
                    _Pragma("unroll")                                           \
                    for (int ni = 0; ni < 4; ++ni)                              \
                        acc[mi][ni] = __builtin_amdgcn_mfma_f32_16x16x32_bf16(  \
                            BUF[mi][h], bf[ni], acc[mi][ni], 0, 0, 0);          \
            }                                                                   \
            __builtin_amdgcn_s_setprio(0);                                      \
        } while (0)

    // Prologue ring fill: issued BEFORE the drain so gather latency hides
    // under the W-DMA drain + barrier (all three are complete at loop entry).
    LOAD_A(aA, 0);
    LOAD_A(aB, 1);
    LOAD_A(aC, 2);

    f32x4 acc[2][4];
    #pragma unroll
    for (int mi = 0; mi < 2; ++mi)
        #pragma unroll
        for (int ni = 0; ni < 4; ++ni) {
            acc[mi][ni][0] = 0.f; acc[mi][ni][1] = 0.f;
            acc[mi][ni][2] = 0.f; acc[mi][ni][3] = 0.f;
        }

    // Handoff: drain ALL VMEM (W-DMA + prologue A + idx/bias), then barrier.
    __builtin_amdgcn_sched_barrier(0);
    asm volatile("s_waitcnt vmcnt(0)" ::: "memory");
    __builtin_amdgcn_sched_barrier(0);
    __syncthreads();   // the ONLY barrier: all W slabs complete

    // Steady state: 12 bytes... 3 LOAD_As (12 loads) in flight; vmcnt(8)
    // retires the oldest LOAD_A (4 loads) just before its COMPUTE.
    COMPUTE(0, aA); LOAD_A(aA, 3);
    COMPUTE(1, aB); LOAD_A(aB, 4);
    COMPUTE(2, aC); LOAD_A(aC, 5);
    WAITA(8); COMPUTE(3, aA); LOAD_A(aA, 6);
    WAITA(8); COMPUTE(4, aB); LOAD_A(aB, 7);
    WAITA(8); COMPUTE(5, aC); LOAD_A(aC, 8);
    WAITA(8); COMPUTE(6, aA);
    WAITA(4); COMPUTE(7, aB);
    WAITA(0); COMPUTE(8, aC);

    #undef LOAD_A
    #undef WAITA
    #undef COMPUTE

    // Epilogue: bias + fast ELU + row-mask + stores.
    // C/D: col = l&15, row = (l>>4)*4 + j per 16x16 frag.
    const int rb = m0 + w * 32 + (l >> 4) * 4;
    const int cb = c0 + (l & 15);
    #pragma unroll
    for (int mi = 0; mi < 2; ++mi) {
        #pragma unroll
        for (int j = 0; j < 4; ++j) {
            const int m = rb + mi * 16 + j;
            if (m < M_TOT) {
                const bool z = ((m % N_) == (N_ - 1));
                float* orow = out + (size_t)m * OUT_ + cb;
                #pragma unroll
                for (int ni = 0; ni < 4; ++ni) {
                    float v = acc[mi][ni][j] + bsv[ni];
                    // fast ELU: v_exp-based, ~1 ulp, fine vs 6.3e-2 threshold
                    const float e = __expf(v) - 1.0f;
                    v = v > 0.f ? v : e;
                    if (z) v = 0.f;
                    orow[ni * 16] = v;
                }
            }
        }
    }
}

extern "C" void kernel_launch(void* const* d_in, const int* in_sizes, int n_in,
                              void* d_out, int out_size, void* d_ws, size_t ws_size,
                              hipStream_t stream) {
    const float* x    = (const float*)d_in[0];
    const void*  adj  = d_in[1];
    const float* W    = (const float*)d_in[2];
    const float* bias = (const float*)d_in[3];
    float* out        = (float*)d_out;

    char* ws = (char*)d_ws;
    unsigned short* xb = (unsigned short*)(ws + WS_XB);
    unsigned short* Wb = (unsigned short*)(ws + WS_WB);

    const int nx8 = X_ELEMS / 8;          // 1,285,888
    const int nw8 = (OUT_ * K_) / 8;      // 9,216
    cvt_xw<<<(nx8 + nw8 + 255) / 256, 256, 0, stream>>>(x, W, xb, Wb, nx8, nw8);

    spiral_mfma<<<1256, 512, 0, stream>>>(xb, adj, Wb, bias, out);
}

// Round 9
// 56.433 us; speedup vs baseline: 1.4931x; 1.2828x over previous
//
#include <hip/hip_runtime.h>
#include <cstdint>
#include <cstddef>

// Problem constants
#define B_    32
#define N_    5023
#define F_    64
#define S_    9
#define OUT_  128
#define M_TOT (B_ * N_)        // 160736
#define K_    (S_ * F_)        // 576

// Workspace layout (bytes)
#define X_ELEMS   (B_ * N_ * F_)          // 10,287,104
#define WS_XB     0                        // bf16 x: 20,574,208 B
#define WS_WB     20574208                 // bf16 W: 147,456 B

typedef __attribute__((ext_vector_type(8))) short          bf16x8;
typedef __attribute__((ext_vector_type(4))) float          f32x4;
typedef __attribute__((ext_vector_type(8))) unsigned short u16x8;

// ---------------------------------------------------------------------------
// Fused fp32->bf16 (RNE) conversion for x and W in one grid.
// ---------------------------------------------------------------------------
__global__ void cvt_xw(const float* __restrict__ x, const float* __restrict__ W,
                       unsigned short* __restrict__ xb, unsigned short* __restrict__ Wb,
                       int nx8, int nw8) {
    const int i = blockIdx.x * blockDim.x + threadIdx.x;
    const float* src;
    unsigned short* dst;
    if (i < nx8) { src = x + (size_t)i * 8; dst = xb + (size_t)i * 8; }
    else {
        const int j = i - nx8;
        if (j >= nw8) return;
        src = W + (size_t)j * 8; dst = Wb + (size_t)j * 8;
    }
    const float4 v0 = ((const float4*)src)[0], v1 = ((const float4*)src)[1];
    const float vv[8] = {v0.x, v0.y, v0.z, v0.w, v1.x, v1.y, v1.z, v1.w};
    u16x8 r;
    #pragma unroll
    for (int k = 0; k < 8; ++k) {
        uint32_t u = __float_as_uint(vv[k]);
        u = u + 0x7fffu + ((u >> 16) & 1u);
        r[k] = (unsigned short)(u >> 16);
    }
    *(u16x8*)dst = r;
}

// ---------------------------------------------------------------------------
// Main MFMA kernel, round-9 structure: block = 128 rows x 128 cols (ALL
// output cols -> each x-row gathered ONCE device-wide, halving the 64-B
// gather traffic that capped rounds 4-8 at ~70us). 8 waves as 4x2, each
// wave 32x64 via 2x4 frags of mfma_f32_16x16x32_bf16.
//
// Per K-step (s = spiral slot, K=64):
//   A-tile [128][64] bf16 gathered straight into LDS via global_load_lds
//     (per-lane random global src, 8 rows x 128 B per inst) - shared by
//     both col-waves. Double-buffered.
//   W-slab [128][64] staged the same way. Double-buffered.
//   Both XOR-chunk-swizzled: phys 16B chunk = logical ^ (row&7), applied
//     on the global source (LDS dest linear) and on the ds_read address.
// Schedule: minimum 2-phase (T3): STAGE(next) -> COMPUTE(cur) ->
//   explicit s_waitcnt vmcnt(0) + __syncthreads(). 2 blocks/CU overlap.
// Output: non-temporal stores (82 MB stream bypasses L2 so gathers stay
//   L2-resident).
// ---------------------------------------------------------------------------
__global__ __launch_bounds__(512, 4)
void spiral_mfma(const unsigned short* __restrict__ xb,
                 const void* __restrict__ adj,
                 const unsigned short* __restrict__ Wb,
                 const float* __restrict__ bias,
                 float* __restrict__ out) {
    __shared__ unsigned short Alds[2][128][64];   // 32 KB
    __shared__ unsigned short Wlds[2][128][64];   // 32 KB

    const int tid = threadIdx.x;
    const int l   = tid & 63;
    const int w   = tid >> 6;                     // 0..7
    const int wr  = w >> 1;                       // compute row-group 0..3
    const int wc  = w & 1;                        // compute col-half 0..1

    // Uniform dtype probe: odd 32-bit words of the first 8 int64 slots are
    // all zero iff adj is int64 (indices < 2^31). Scalar loads, broadcast.
    const int* aw = (const int*)adj;
    const int pv = aw[1] | aw[3] | aw[5] | aw[7] | aw[9] | aw[11] | aw[13] | aw[15];
    const int sh = (pv == 0) ? 3 : 2;             // byte shift per element
    const char* adjp = (const char*)adj;

    // XCD-chunked bijective swizzle: 1256 = 8 * 157 exactly.
    const int bid = blockIdx.x;
    const int nb  = (bid & 7) * 157 + (bid >> 3);
    const int m0  = nb * 128;

    // Staging assignment: wave w sources A rows / W rows [w*16, w*16+16),
    // two issues of 8 rows; lane l -> row +(l>>3), phys chunk (l&7).
    // Pre-swizzled source chunk (involution): c_swz = (l&7) ^ ((l>>3)&7).
    const int c_swz = (l & 7) ^ ((l >> 3) & 7);

    // Per-thread staging metadata: 2 rows (one per issue), all 9 indices.
    uint32_t xr[2];
    int      idxv[2][S_];
    #pragma unroll
    for (int i = 0; i < 2; ++i) {
        int r = m0 + w * 16 + i * 8 + (l >> 3);
        if (r >= M_TOT) r = M_TOT - 1;
        xr[i] = (uint32_t)(r / N_) * (N_ * F_);
        const int base = r * S_;
        #pragma unroll
        for (int s = 0; s < S_; ++s)
            idxv[i][s] = *(const int*)(adjp + ((size_t)(base + s) << sh));
    }

    #define STAGE(buf_, s_)                                                     \
        do {                                                                    \
            _Pragma("unroll")                                                   \
            for (int i_ = 0; i_ < 2; ++i_) {                                    \
                const unsigned short* srcA = xb + xr[i_] +                      \
                    (uint32_t)idxv[i_][(s_)] * F_ + c_swz * 8;                  \
                unsigned short* dstA = &Alds[(buf_)][w * 16 + i_ * 8][0];       \
                __builtin_amdgcn_global_load_lds(                               \
                    (const __attribute__((address_space(1))) void*)srcA,        \
                    (__attribute__((address_space(3))) void*)dstA, 16, 0, 0);   \
                const unsigned short* srcW = Wb +                               \
                    (size_t)(w * 16 + i_ * 8 + (l >> 3)) * K_ + (s_) * F_ +     \
                    c_swz * 8;                                                  \
                unsigned short* dstW = &Wlds[(buf_)][w * 16 + i_ * 8][0];       \
                __builtin_amdgcn_global_load_lds(                               \
                    (const __attribute__((address_space(1))) void*)srcW,        \
                    (__attribute__((address_space(3))) void*)dstW, 16, 0, 0);   \
            }                                                                   \
        } while (0)

    #define DRAIN                                                               \
        do {                                                                    \
            __builtin_amdgcn_sched_barrier(0);                                  \
            asm volatile("s_waitcnt vmcnt(0)" ::: "memory");                    \
            __builtin_amdgcn_sched_barrier(0);                                  \
        } while (0)

    // Compute: wave tile 32x64. Frag rows (A) and frag rows-of-W (B) both
    // have row&7 == l&7, so one swizzled chunk offset serves both.
    #define COMPUTE(buf_)                                                       \
        do {                                                                    \
            _Pragma("unroll")                                                   \
            for (int h = 0; h < 2; ++h) {                                       \
                const int pc = ((h * 4 + (l >> 4)) ^ (l & 7)) * 8;              \
                bf16x8 av[2], bv[4];                                            \
                _Pragma("unroll")                                               \
                for (int mi = 0; mi < 2; ++mi)                                  \
                    av[mi] = *(const bf16x8*)                                   \
                        &Alds[(buf_)][wr * 32 + mi * 16 + (l & 15)][pc];        \
                _Pragma("unroll")                                               \
                for (int ni = 0; ni < 4; ++ni)                                  \
                    bv[ni] = *(const bf16x8*)                                   \
                        &Wlds[(buf_)][wc * 64 + ni * 16 + (l & 15)][pc];        \
                _Pragma("unroll")                                               \
                for (int mi = 0; mi < 2; ++mi)                                  \
                    _Pragma("unroll")                                           \
                    for (int ni = 0; ni < 4; ++ni)                              \
                        acc[mi][ni] = __builtin_amdgcn_mfma_f32_16x16x32_bf16(  \
                            av[mi], bv[ni], acc[mi][ni], 0, 0, 0);              \
            }                                                                   \
        } while (0)

    f32x4 acc[2][4];
    #pragma unroll
    for (int mi = 0; mi < 2; ++mi)
        #pragma unroll
        for (int ni = 0; ni < 4; ++ni) {
            acc[mi][ni][0] = 0.f; acc[mi][ni][1] = 0.f;
            acc[mi][ni][2] = 0.f; acc[mi][ni][3] = 0.f;
        }

    // Prologue: stage step 0, drain, barrier.
    STAGE(0, 0);
    DRAIN;
    __syncthreads();

    // 2-phase main loop: stage next while computing current.
    #pragma unroll
    for (int s = 0; s < S_; ++s) {
        if (s < S_ - 1) STAGE((s + 1) & 1, s + 1);
        COMPUTE(s & 1);
        if (s < S_ - 1) {
            DRAIN;
            __syncthreads();
        }
    }

    #undef STAGE
    #undef DRAIN
    #undef COMPUTE

    // Epilogue: bias + fast ELU + row-mask + NON-TEMPORAL stores (keep the
    // 82 MB output stream out of L2 so the gather working set stays hot).
    float bs[4];
    #pragma unroll
    for (int ni = 0; ni < 4; ++ni) bs[ni] = bias[wc * 64 + ni * 16 + (l & 15)];

    const int rb = m0 + wr * 32 + (l >> 4) * 4;
    const int cb = wc * 64 + (l & 15);
    #pragma unroll
    for (int mi = 0; mi < 2; ++mi) {
        #pragma unroll
        for (int j = 0; j < 4; ++j) {
            const int m = rb + mi * 16 + j;
            if (m < M_TOT) {
                const bool z = ((m % N_) == (N_ - 1));
                float* orow = out + (size_t)m * OUT_ + cb;
                #pragma unroll
                for (int ni = 0; ni < 4; ++ni) {
                    float v = acc[mi][ni][j] + bs[ni];
                    const float e = __expf(v) - 1.0f;   // fast ELU
                    v = v > 0.f ? v : e;
                    if (z) v = 0.f;
                    __builtin_nontemporal_store(v, &orow[ni * 16]);
                }
            }
        }
    }
}

extern "C" void kernel_launch(void* const* d_in, const int* in_sizes, int n_in,
                              void* d_out, int out_size, void* d_ws, size_t ws_size,
                              hipStream_t stream) {
    const float* x    = (const float*)d_in[0];
    const void*  adj  = d_in[1];
    const float* W    = (const float*)d_in[2];
    const float* bias = (const float*)d_in[3];
    float* out        = (float*)d_out;

    char* ws = (char*)d_ws;
    unsigned short* xb = (unsigned short*)(ws + WS_XB);
    unsigned short* Wb = (unsigned short*)(ws + WS_WB);

    const int nx8 = X_ELEMS / 8;          // 1,285,888
    const int nw8 = (OUT_ * K_) / 8;      // 9,216
    cvt_xw<<<(nx8 + nw8 + 255) / 256, 256, 0, stream>>>(x, W, xb, Wb, nx8, nw8);

    const int grid = (M_TOT + 127) / 128; // 1256 = 8 * 157
    spiral_mfma<<<grid, 512, 0, stream>>>(xb, adj, Wb, bias, out);
}